// Round 10
// baseline (458.691 us; speedup 1.0000x reference)
//
#include <hip/hip_runtime.h>
#include <hip/hip_bf16.h>
#include <cstdint>

typedef unsigned short u16;
typedef unsigned int   u32;

typedef __attribute__((ext_vector_type(8))) short short8;   // 8 x bf16 (4 VGPRs)
typedef __attribute__((ext_vector_type(4))) float f32x4;    // MFMA accumulator

__device__ __forceinline__ float b2f(u16 v) { return __uint_as_float(((u32)v) << 16); }
__device__ __forceinline__ u16 f2b(float f) {
    u32 u = __float_as_uint(f);
    u += 0x7FFFu + ((u >> 16) & 1u);   // round-to-nearest-even
    return (u16)(u >> 16);
}

#define G2L16(gp, lp) __builtin_amdgcn_global_load_lds(                       \
    (const __attribute__((address_space(1))) void*)(gp),                      \
    (__attribute__((address_space(3))) void*)(lp), 16, 0, 0)

// ---------------------------------------------------------------------------
// Grid barrier (r8-proven: passed correctness under graph replay).
// Release: __syncthreads -> agent fence -> atomic arrive.
// Acquire: spin on generation -> agent fence -> __syncthreads.
// ---------------------------------------------------------------------------
__device__ __forceinline__ void grid_barrier(u32* bar, u32* gen, u32 nb) {
    __syncthreads();
    if (threadIdx.x == 0) {
        __threadfence();                                   // release
        const u32 g = __hip_atomic_load(gen, __ATOMIC_RELAXED,
                                        __HIP_MEMORY_SCOPE_AGENT);
        const u32 t = atomicAdd(bar, 1u);                  // device scope
        if (t == nb - 1u) {
            *bar = 0u;                                     // reset before bump
            __threadfence();
            atomicAdd(gen, 1u);                            // release generation
        } else {
            while (__hip_atomic_load(gen, __ATOMIC_RELAXED,
                                     __HIP_MEMORY_SCOPE_AGENT) == g)
                __builtin_amdgcn_s_sleep(4);
        }
        __threadfence();                                   // acquire
    }
    __syncthreads();
}

// ---------------------------------------------------------------------------
// Fused prologue (standalone dispatch, native 14848-block geometry):
//   [0,1024) W1->W1t, [1024,2048) W2->W2t, [2048,6144) Wg->Wgt,
//   [6144,14336) iQ cast, [14336,14848) iV chunk sums (16-row chunks).
// ---------------------------------------------------------------------------
__device__ __forceinline__ void transpose_body(const float* __restrict__ in,
                                               u16* __restrict__ out,
                                               int R, int C, int lb, int tilesX,
                                               float (*tile)[33]) {
    const int bx = (lb % tilesX) * 32;
    const int by = (lb / tilesX) * 32;
    const int tx = threadIdx.x & 31, ty = threadIdx.x >> 5;   // 32 x 8
    #pragma unroll
    for (int i = 0; i < 32; i += 8)
        tile[ty + i][tx] = in[(size_t)(by + ty + i) * C + (bx + tx)];
    __syncthreads();
    #pragma unroll
    for (int i = 0; i < 32; i += 8)
        out[(size_t)(bx + ty + i) * R + (by + tx)] = f2b(tile[tx][ty + i]);
}

__global__ void prologue_kernel(const float* __restrict__ W1, u16* __restrict__ W1t,
                                const float* __restrict__ W2, u16* __restrict__ W2t,
                                const float* __restrict__ Wg, u16* __restrict__ Wgt,
                                const float* __restrict__ iQ, u16* __restrict__ iQb,
                                const float* __restrict__ iV, float* __restrict__ csum) {
    __shared__ float tile[32][33];
    const int bid = blockIdx.x;
    const int tid = threadIdx.x;
    if (bid < 1024) {
        transpose_body(W1, W1t, 1024, 1024, bid, 32, tile);
    } else if (bid < 2048) {
        transpose_body(W2, W2t, 1024, 1024, bid - 1024, 32, tile);
    } else if (bid < 6144) {
        transpose_body(Wg, Wgt, 2048, 2048, bid - 2048, 64, tile);
    } else if (bid < 14336) {
        const size_t i = ((size_t)(bid - 6144) * 256 + tid) * 4;
        const float4 v = *(const float4*)(iQ + i);
        ushort4 o;
        o.x = f2b(v.x); o.y = f2b(v.y); o.z = f2b(v.z); o.w = f2b(v.w);
        *(ushort4*)(iQb + i) = o;
    } else {
        const int idx = bid - 14336;
        const int b = idx >> 7, c = idx & 127;
        const int d = tid * 4;                              // D = 1024
        const float* src = iV + ((size_t)(b * 2048 + c * 16)) * 1024 + d;
        float4 s = {0.f, 0.f, 0.f, 0.f};
        #pragma unroll 8
        for (int i = 0; i < 16; ++i) {
            const float4 v = *(const float4*)(src + (size_t)i * 1024);
            s.x += v.x; s.y += v.y; s.z += v.z; s.w += v.w;
        }
        *(float4*)(csum + ((size_t)(b * 128 + c)) * 1024 + d) = s;
    }
}

// ---------------------------------------------------------------------------
// GEMM phase (r6/r9-verified BK=128 body): C = EPI(A @ Bt^T + bias).
// M=8192, N=1024, K=1024. Block b -> m0=(b&63)*128 (m-fast: xcd=m%8), n0=(b>>6)*128.
// ---------------------------------------------------------------------------
template <int EPI>
__device__ __forceinline__ void gemm128_phase(const u16* __restrict__ A,
                                              const u16* __restrict__ Bt,
                                              const float* __restrict__ bias,
                                              u16* __restrict__ C,
                                              u16 (*lds)[8192], int b, int tid) {
    const int K = 1024, N = 1024;
    const int m0   = (b & 63) * 128;
    const int n0   = (b >> 6) * 128;
    const int wave = tid >> 6, lane = tid & 63;
    const int wm   = (wave & 1) << 6;
    const int wn   = (wave >> 1) << 6;
    const int quad = lane >> 4, l16 = lane & 15;

    f32x4 acc[4][4];
    #pragma unroll
    for (int i = 0; i < 4; ++i)
        #pragma unroll
        for (int j = 0; j < 4; ++j) acc[i][j] = (f32x4){0.f, 0.f, 0.f, 0.f};

    int oo[4], rr[4], qq[4];
    #pragma unroll
    for (int j = 0; j < 4; ++j) {
        oo[j] = tid * 16 + j * 4096;
        rr[j] = oo[j] >> 7;
        qq[j] = ((oo[j] >> 4) & 7) ^ (rr[j] & 7);
    }

    for (int kt = 0; kt < (K >> 7); ++kt) {
        const int kb = kt << 7;
        #pragma unroll
        for (int kk = 0; kk < 2; ++kk) {
            const int kbk = kb + kk * 64;
            #pragma unroll
            for (int j = 0; j < 4; ++j) {
                G2L16((const char*)A  + ((size_t)(m0 + rr[j]) * K + kbk) * 2 + qq[j] * 16,
                      (char*)&lds[kk][0] + oo[j]);
                G2L16((const char*)Bt + ((size_t)(n0 + rr[j]) * K + kbk) * 2 + qq[j] * 16,
                      (char*)&lds[2 + kk][0] + oo[j]);
            }
        }
        __syncthreads();

        #pragma unroll
        for (int kk = 0; kk < 2; ++kk) {
            #pragma unroll
            for (int h = 0; h < 2; ++h) {
                short8 af[4], bf[4];
                #pragma unroll
                for (int mi = 0; mi < 4; ++mi) {
                    const int R = wm + mi * 16 + l16;
                    af[mi] = *(const short8*)(&lds[kk][0] + R * 64 +
                                              ((((h << 2) | quad) ^ (R & 7)) << 3));
                }
                #pragma unroll
                for (int ni = 0; ni < 4; ++ni) {
                    const int R = wn + ni * 16 + l16;
                    bf[ni] = *(const short8*)(&lds[2 + kk][0] + R * 64 +
                                              ((((h << 2) | quad) ^ (R & 7)) << 3));
                }
                #pragma unroll
                for (int mi = 0; mi < 4; ++mi)
                    #pragma unroll
                    for (int ni = 0; ni < 4; ++ni)
                        acc[mi][ni] = __builtin_amdgcn_mfma_f32_16x16x32_bf16(
                            af[mi], bf[ni], acc[mi][ni], 0, 0, 0);
            }
        }
        __syncthreads();
    }

    #pragma unroll
    for (int ni = 0; ni < 4; ++ni) {
        const int col = n0 + wn + ni * 16 + l16;
        const float bv = bias[col];
        #pragma unroll
        for (int mi = 0; mi < 4; ++mi) {
            const int row0 = m0 + wm + mi * 16 + quad * 4;
            #pragma unroll
            for (int r = 0; r < 4; ++r) {
                float v = acc[mi][ni][r] + bv;
                if (EPI == 0) v = fmaxf(v, 0.f);
                C[(size_t)(row0 + r) * N + col] = f2b(v);
            }
        }
    }
}

// ---------------------------------------------------------------------------
// Gate phase (r9-verified body, bf16-iQ epilogue).
// ---------------------------------------------------------------------------
__device__ __forceinline__ void gate_phase(const u16* __restrict__ iQb,
                                           const u16* __restrict__ ffn,
                                           const u16* __restrict__ Wgt,
                                           const float* __restrict__ bg,
                                           float* __restrict__ out,
                                           u16 (*lds)[8192], int b, int tid) {
    const int D2 = 2048, D = 1024;
    const int m0   = (b & 63) * 128;
    const int n0   = (b >> 6) * 128;
    const int wave = tid >> 6, lane = tid & 63;
    const int wm   = (wave & 1) << 6;
    const int wn   = (wave >> 1) << 6;
    const int quad = lane >> 4, l16 = lane & 15;

    f32x4 acc[2][4][4];
    #pragma unroll
    for (int p = 0; p < 2; ++p)
        #pragma unroll
        for (int i = 0; i < 4; ++i)
            #pragma unroll
            for (int j = 0; j < 4; ++j) acc[p][i][j] = (f32x4){0.f, 0.f, 0.f, 0.f};

    int oo[4], rr[4], qq[4];
    #pragma unroll
    for (int j = 0; j < 4; ++j) {
        oo[j] = tid * 16 + j * 4096;
        rr[j] = oo[j] >> 7;
        qq[j] = ((oo[j] >> 4) & 7) ^ (rr[j] & 7);
    }

    for (int kt = 0; kt < (D2 >> 6); ++kt) {
        const int kb = kt << 6;
        const char* Ab = (const char*)((kb < D) ? (iQb + kb) : (ffn + (kb - D)));
        const char* B0 = (const char*)(Wgt + (size_t)n0 * D2 + kb);
        const char* B1 = (const char*)(Wgt + (size_t)(n0 + D) * D2 + kb);
        #pragma unroll
        for (int j = 0; j < 4; ++j) {
            G2L16(Ab + (size_t)(m0 + rr[j]) * D * 2 + qq[j] * 16, (char*)&lds[0][0] + oo[j]);
            G2L16(B0 + (size_t)rr[j] * D2 * 2 + qq[j] * 16,       (char*)&lds[1][0] + oo[j]);
            G2L16(B1 + (size_t)rr[j] * D2 * 2 + qq[j] * 16,       (char*)&lds[2][0] + oo[j]);
        }
        __syncthreads();

        #pragma unroll
        for (int h = 0; h < 2; ++h) {
            short8 af[4], bf0[4], bf1[4];
            #pragma unroll
            for (int mi = 0; mi < 4; ++mi) {
                const int R = wm + mi * 16 + l16;
                af[mi] = *(const short8*)(&lds[0][0] + R * 64 +
                                          ((((h << 2) | quad) ^ (R & 7)) << 3));
            }
            #pragma unroll
            for (int ni = 0; ni < 4; ++ni) {
                const int R = wn + ni * 16 + l16;
                const int so = R * 64 + ((((h << 2) | quad) ^ (R & 7)) << 3);
                bf0[ni] = *(const short8*)(&lds[1][0] + so);
                bf1[ni] = *(const short8*)(&lds[2][0] + so);
            }
            #pragma unroll
            for (int mi = 0; mi < 4; ++mi)
                #pragma unroll
                for (int ni = 0; ni < 4; ++ni) {
                    acc[0][mi][ni] = __builtin_amdgcn_mfma_f32_16x16x32_bf16(
                        af[mi], bf0[ni], acc[0][mi][ni], 0, 0, 0);
                    acc[1][mi][ni] = __builtin_amdgcn_mfma_f32_16x16x32_bf16(
                        af[mi], bf1[ni], acc[1][mi][ni], 0, 0, 0);
                }
        }
        __syncthreads();
    }

    #pragma unroll
    for (int ni = 0; ni < 4; ++ni) {
        const int col = n0 + wn + ni * 16 + l16;
        const float bgi = bg[col];
        const float bgf = bg[col + D];
        #pragma unroll
        for (int mi = 0; mi < 4; ++mi) {
            const int row0 = m0 + wm + mi * 16 + quad * 4;
            #pragma unroll
            for (int r = 0; r < 4; ++r) {
                const size_t idx = (size_t)(row0 + r) * D + col;
                const float gi = 1.0f / (1.0f + __expf(-(acc[0][mi][ni][r] + bgi)));
                const float gf = 1.0f / (1.0f + __expf(-(acc[1][mi][ni][r] + bgf)));
                out[idx] = gi * b2f(iQb[idx]) + gf * b2f(ffn[idx]);
            }
        }
    }
}

// ---------------------------------------------------------------------------
// Fused {scan, gemm0, gemm1, gate}: all four phases natively run at
// 512 blocks x 256 threads / 2 blocks/CU — identical occupancy to their
// standalone dispatches (this is what r8 got wrong only for the prologue).
// 3 grid barriers replace 3 inter-dispatch gaps (~9 us each).
// ---------------------------------------------------------------------------
__global__ __launch_bounds__(256, 2)
void fused_kernel(const float* __restrict__ iV, const float* __restrict__ csum,
                  const u16* __restrict__ iQb, const u16* __restrict__ W1t,
                  const u16* __restrict__ W2t, const u16* __restrict__ Wgt,
                  const float* __restrict__ b1, const float* __restrict__ b2,
                  const float* __restrict__ bg, float* __restrict__ out,
                  u16* __restrict__ regA, u16* __restrict__ regB,
                  u32* __restrict__ bar) {
    __shared__ u16 lds[4][8192];   // 64 KB -> exactly 2 blocks/CU, 512 co-resident

    const int b   = blockIdx.x;    // 0..511
    const int tid = threadIdx.x;
    u32* gen = bar + 1;

    // ---- P0: scan (prefix over chunk sums + in-chunk serial) -> avg = regA ----
    {
        const int c = b & 127, bb = b >> 7;
        const int d = tid * 4;
        const float* cs = csum + (size_t)bb * 128 * 1024 + d;
        float4 a0 = {0,0,0,0}, a1 = {0,0,0,0}, a2 = {0,0,0,0}, a3 = {0,0,0,0};
        int cc = 0;
        for (; cc + 4 <= c; cc += 4) {
            const float4 v0 = *(const float4*)(cs + (size_t)(cc + 0) * 1024);
            const float4 v1 = *(const float4*)(cs + (size_t)(cc + 1) * 1024);
            const float4 v2 = *(const float4*)(cs + (size_t)(cc + 2) * 1024);
            const float4 v3 = *(const float4*)(cs + (size_t)(cc + 3) * 1024);
            a0.x += v0.x; a0.y += v0.y; a0.z += v0.z; a0.w += v0.w;
            a1.x += v1.x; a1.y += v1.y; a1.z += v1.z; a1.w += v1.w;
            a2.x += v2.x; a2.y += v2.y; a2.z += v2.z; a2.w += v2.w;
            a3.x += v3.x; a3.y += v3.y; a3.z += v3.z; a3.w += v3.w;
        }
        for (; cc < c; ++cc) {
            const float4 v = *(const float4*)(cs + (size_t)cc * 1024);
            a0.x += v.x; a0.y += v.y; a0.z += v.z; a0.w += v.w;
        }
        float4 acc;
        acc.x = (a0.x + a1.x) + (a2.x + a3.x);
        acc.y = (a0.y + a1.y) + (a2.y + a3.y);
        acc.z = (a0.z + a1.z) + (a2.z + a3.z);
        acc.w = (a0.w + a1.w) + (a2.w + a3.w);

        const size_t off = ((size_t)(bb * 2048 + c * 16)) * 1024 + d;
        const float* src = iV + off;
        u16*         dst = regA + off;            // avg
        const int s0 = c * 16;
        #pragma unroll 4
        for (int i2 = 0; i2 < 16; ++i2) {
            const float4 v = *(const float4*)(src + (size_t)i2 * 1024);
            acc.x += v.x; acc.y += v.y; acc.z += v.z; acc.w += v.w;
            const float inv = 1.0f / (float)(s0 + i2 + 1);
            ushort4 o;
            o.x = f2b(acc.x * inv); o.y = f2b(acc.y * inv);
            o.z = f2b(acc.z * inv); o.w = f2b(acc.w * inv);
            *(ushort4*)(dst + (size_t)i2 * 1024) = o;
        }
    }
    grid_barrier(bar, gen, 512);

    // ---- P1: h = relu(avg @ W1 + b1) ----
    gemm128_phase<0>(regA, W1t, b1, regB, lds, b, tid);
    grid_barrier(bar, gen, 512);

    // ---- P2: ffn = h @ W2 + b2 (overlays avg) ----
    gemm128_phase<1>(regB, W2t, b2, regA, lds, b, tid);
    grid_barrier(bar, gen, 512);

    // ---- P3: fused gate GEMM + sigmoid-gate epilogue ----
    gate_phase(iQb, regA, Wgt, bg, out, lds, b, tid);
}

// ---------------------------------------------------------------------------
extern "C" void kernel_launch(void* const* d_in, const int* in_sizes, int n_in,
                              void* d_out, int out_size, void* d_ws, size_t ws_size,
                              hipStream_t stream) {
    const int D = 1024, D2 = 2048;
    const int M = 8192;

    const float* iQ = (const float*)d_in[0];
    const float* iV = (const float*)d_in[1];
    const float* W1 = (const float*)d_in[2];
    const float* b1 = (const float*)d_in[3];
    const float* W2 = (const float*)d_in[4];
    const float* b2 = (const float*)d_in[5];
    const float* Wg = (const float*)d_in[6];
    const float* bg = (const float*)d_in[7];
    float* out = (float*)d_out;

    // workspace, no aliasing (62 MB + barrier):
    u16*   regA = (u16*)d_ws;                      // avg -> ffn   (16 MB)
    u16*   regB = regA + (size_t)M * D;            // h            (16 MB)
    u16*   iQb  = regB + (size_t)M * D;            // iQ bf16      (16 MB)
    u16*   W1t  = iQb  + (size_t)M * D;            //              ( 2 MB)
    u16*   W2t  = W1t  + (size_t)D * D;            //              ( 2 MB)
    u16*   Wgt  = W2t  + (size_t)D * D;            //              ( 8 MB)
    float* csum = (float*)(Wgt + (size_t)D2 * D2); // B*128*D f32  ( 2 MB)
    u32*   bar  = (u32*)(csum + (size_t)4 * 128 * 1024); // [bar, gen]

    hipMemsetAsync(bar, 0, 2 * sizeof(u32), stream);
    // 1. independent prologue work at its native wide geometry (14848 blocks)
    prologue_kernel<<<14848, 256, 0, stream>>>(W1, W1t, W2, W2t, Wg, Wgt,
                                               iQ, iQb, iV, csum);
    // 2. scan + gemm0 + gemm1 + gate in ONE dispatch (512 blocks, 3 grid barriers)
    fused_kernel<<<512, 256, 0, stream>>>(iV, csum, iQb, W1t, W2t, Wgt,
                                          b1, b2, bg, out, regA, regB, bar);
}

// Round 11
// 259.638 us; speedup vs baseline: 1.7667x; 1.7667x over previous
//
#include <hip/hip_runtime.h>
#include <hip/hip_bf16.h>
#include <cstdint>

typedef unsigned short u16;
typedef unsigned int   u32;

typedef __attribute__((ext_vector_type(8))) short short8;   // 8 x bf16 (4 VGPRs)
typedef __attribute__((ext_vector_type(4))) float f32x4;    // MFMA accumulator

__device__ __forceinline__ float b2f(u16 v) { return __uint_as_float(((u32)v) << 16); }
__device__ __forceinline__ u16 f2b(float f) {
    u32 u = __float_as_uint(f);
    u += 0x7FFFu + ((u >> 16) & 1u);   // round-to-nearest-even
    return (u16)(u >> 16);
}

#define G2L16(gp, lp) __builtin_amdgcn_global_load_lds(                       \
    (const __attribute__((address_space(1))) void*)(gp),                      \
    (__attribute__((address_space(3))) void*)(lp), 16, 0, 0)

// ---------------------------------------------------------------------------
// Fused prologue (one dispatch):
//   blocks [0,1024)      : W1 -> W1t (bf16, transposed)
//   blocks [1024,2048)   : W2 -> W2t
//   blocks [2048,6144)   : Wg -> Wgt
//   blocks [6144,14336)  : cast iQ f32 -> iQb bf16
//   blocks [14336,14848) : chunk sums of iV (128 chunks of 16 rows per batch)
// ---------------------------------------------------------------------------
__device__ __forceinline__ void transpose_body(const float* __restrict__ in,
                                               u16* __restrict__ out,
                                               int R, int C, int lb, int tilesX,
                                               float (*tile)[33]) {
    const int bx = (lb % tilesX) * 32;
    const int by = (lb / tilesX) * 32;
    const int tx = threadIdx.x & 31, ty = threadIdx.x >> 5;   // 32 x 8
    #pragma unroll
    for (int i = 0; i < 32; i += 8)
        tile[ty + i][tx] = in[(size_t)(by + ty + i) * C + (bx + tx)];
    __syncthreads();
    #pragma unroll
    for (int i = 0; i < 32; i += 8)
        out[(size_t)(bx + ty + i) * R + (by + tx)] = f2b(tile[tx][ty + i]);
}

__global__ void prologue_kernel(const float* __restrict__ W1, u16* __restrict__ W1t,
                                const float* __restrict__ W2, u16* __restrict__ W2t,
                                const float* __restrict__ Wg, u16* __restrict__ Wgt,
                                const float* __restrict__ iQ, u16* __restrict__ iQb,
                                const float* __restrict__ iV, float* __restrict__ csum) {
    __shared__ float tile[32][33];
    const int bid = blockIdx.x;
    const int tid = threadIdx.x;
    if (bid < 1024) {
        transpose_body(W1, W1t, 1024, 1024, bid, 32, tile);
    } else if (bid < 2048) {
        transpose_body(W2, W2t, 1024, 1024, bid - 1024, 32, tile);
    } else if (bid < 6144) {
        transpose_body(Wg, Wgt, 2048, 2048, bid - 2048, 64, tile);
    } else if (bid < 14336) {
        const size_t i = ((size_t)(bid - 6144) * 256 + tid) * 4;
        const float4 v = *(const float4*)(iQ + i);
        ushort4 o;
        o.x = f2b(v.x); o.y = f2b(v.y); o.z = f2b(v.z); o.w = f2b(v.w);
        *(ushort4*)(iQb + i) = o;
    } else {
        // chunk sums: 16-row chunks, 128 chunks per batch, 4 batches -> 512 blocks
        const int idx = bid - 14336;
        const int b = idx >> 7, c = idx & 127;
        const int d = tid * 4;                              // D = 1024
        const float* src = iV + ((size_t)(b * 2048 + c * 16)) * 1024 + d;
        float4 s = {0.f, 0.f, 0.f, 0.f};
        #pragma unroll 8
        for (int i = 0; i < 16; ++i) {
            const float4 v = *(const float4*)(src + (size_t)i * 1024);
            s.x += v.x; s.y += v.y; s.z += v.z; s.w += v.w;
        }
        *(float4*)(csum + ((size_t)(b * 128 + c)) * 1024 + d) = s;
    }
}

// ---------------------------------------------------------------------------
// Scan: prefix over chunk sums (4-way ILP) + in-chunk serial scan -> avg bf16.
// 16-row chunks -> 512 blocks (8 waves/CU).
// ---------------------------------------------------------------------------
__global__ void scan_kernel(const float* __restrict__ iV, const float* __restrict__ csum,
                            u16* __restrict__ avg) {
    const int c = blockIdx.x & 127, b = blockIdx.x >> 7;
    const int d = threadIdx.x * 4;
    const float* cs = csum + (size_t)b * 128 * 1024 + d;
    float4 a0 = {0,0,0,0}, a1 = {0,0,0,0}, a2 = {0,0,0,0}, a3 = {0,0,0,0};
    int cc = 0;
    for (; cc + 4 <= c; cc += 4) {
        const float4 v0 = *(const float4*)(cs + (size_t)(cc + 0) * 1024);
        const float4 v1 = *(const float4*)(cs + (size_t)(cc + 1) * 1024);
        const float4 v2 = *(const float4*)(cs + (size_t)(cc + 2) * 1024);
        const float4 v3 = *(const float4*)(cs + (size_t)(cc + 3) * 1024);
        a0.x += v0.x; a0.y += v0.y; a0.z += v0.z; a0.w += v0.w;
        a1.x += v1.x; a1.y += v1.y; a1.z += v1.z; a1.w += v1.w;
        a2.x += v2.x; a2.y += v2.y; a2.z += v2.z; a2.w += v2.w;
        a3.x += v3.x; a3.y += v3.y; a3.z += v3.z; a3.w += v3.w;
    }
    for (; cc < c; ++cc) {
        const float4 v = *(const float4*)(cs + (size_t)cc * 1024);
        a0.x += v.x; a0.y += v.y; a0.z += v.z; a0.w += v.w;
    }
    float4 acc;
    acc.x = (a0.x + a1.x) + (a2.x + a3.x);
    acc.y = (a0.y + a1.y) + (a2.y + a3.y);
    acc.z = (a0.z + a1.z) + (a2.z + a3.z);
    acc.w = (a0.w + a1.w) + (a2.w + a3.w);

    const size_t off = ((size_t)(b * 2048 + c * 16)) * 1024 + d;
    const float* src = iV + off;
    u16*         dst = avg + off;
    const int s0 = c * 16;
    #pragma unroll 4
    for (int i = 0; i < 16; ++i) {
        const float4 v = *(const float4*)(src + (size_t)i * 1024);
        acc.x += v.x; acc.y += v.y; acc.z += v.z; acc.w += v.w;
        const float inv = 1.0f / (float)(s0 + i + 1);
        ushort4 o;
        o.x = f2b(acc.x * inv); o.y = f2b(acc.y * inv);
        o.z = f2b(acc.z * inv); o.w = f2b(acc.w * inv);
        *(ushort4*)(dst + (size_t)i * 1024) = o;
    }
}

// ---------------------------------------------------------------------------
// MFMA GEMM, BK=128 as two adjacent BK=64 sub-tiles per barrier window
// (identical proven swizzle per sub-tile; 64 MFMA/wave per window, 8 windows
// at K=1024 vs 16 -> barrier-drain amortized 2x). LDS 64KB -> 2 blocks/CU.
// EPI: 0 = relu(x+b), 1 = x+b.
// ---------------------------------------------------------------------------
template <int EPI>
__global__ __launch_bounds__(256, 2)
void gemm_kernel(const u16* __restrict__ A, const u16* __restrict__ Bt,
                 const float* __restrict__ bias, u16* __restrict__ C,
                 int M, int N, int K) {
    __shared__ u16 As[2][128 * 64];
    __shared__ u16 Bs[2][128 * 64];

    const int tid  = threadIdx.x;
    const int m0   = blockIdx.x * 128;
    const int n0   = blockIdx.y * 128;
    const int wave = tid >> 6, lane = tid & 63;
    const int wm   = (wave & 1) << 6;
    const int wn   = (wave >> 1) << 6;
    const int quad = lane >> 4, l16 = lane & 15;

    f32x4 acc[4][4];
    #pragma unroll
    for (int i = 0; i < 4; ++i)
        #pragma unroll
        for (int j = 0; j < 4; ++j) acc[i][j] = (f32x4){0.f, 0.f, 0.f, 0.f};

    int oo[4], rr[4], qq[4];
    #pragma unroll
    for (int j = 0; j < 4; ++j) {
        oo[j] = tid * 16 + j * 4096;
        rr[j] = oo[j] >> 7;
        qq[j] = ((oo[j] >> 4) & 7) ^ (rr[j] & 7);
    }

    const int ktiles = K >> 7;                  // BK=128 -> 8 windows
    for (int kt = 0; kt < ktiles; ++kt) {
        const int kb = kt << 7;
        #pragma unroll
        for (int kk = 0; kk < 2; ++kk) {
            const int kbk = kb + kk * 64;
            #pragma unroll
            for (int j = 0; j < 4; ++j) {
                G2L16((const char*)A  + ((size_t)(m0 + rr[j]) * K + kbk) * 2 + qq[j] * 16,
                      (char*)&As[kk][0] + oo[j]);
                G2L16((const char*)Bt + ((size_t)(n0 + rr[j]) * K + kbk) * 2 + qq[j] * 16,
                      (char*)&Bs[kk][0] + oo[j]);
            }
        }
        __syncthreads();

        #pragma unroll
        for (int kk = 0; kk < 2; ++kk) {
            #pragma unroll
            for (int h = 0; h < 2; ++h) {
                short8 af[4], bf[4];
                #pragma unroll
                for (int mi = 0; mi < 4; ++mi) {
                    const int R = wm + mi * 16 + l16;
                    af[mi] = *(const short8*)(&As[kk][0] + R * 64 +
                                              ((((h << 2) | quad) ^ (R & 7)) << 3));
                }
                #pragma unroll
                for (int ni = 0; ni < 4; ++ni) {
                    const int R = wn + ni * 16 + l16;
                    bf[ni] = *(const short8*)(&Bs[kk][0] + R * 64 +
                                              ((((h << 2) | quad) ^ (R & 7)) << 3));
                }
                #pragma unroll
                for (int mi = 0; mi < 4; ++mi)
                    #pragma unroll
                    for (int ni = 0; ni < 4; ++ni)
                        acc[mi][ni] = __builtin_amdgcn_mfma_f32_16x16x32_bf16(
                            af[mi], bf[ni], acc[mi][ni], 0, 0, 0);
            }
        }
        __syncthreads();
    }

    #pragma unroll
    for (int ni = 0; ni < 4; ++ni) {
        const int col = n0 + wn + ni * 16 + l16;
        const float bv = bias[col];
        #pragma unroll
        for (int mi = 0; mi < 4; ++mi) {
            const int row0 = m0 + wm + mi * 16 + quad * 4;
            #pragma unroll
            for (int r = 0; r < 4; ++r) {
                float v = acc[mi][ni][r] + bv;
                if (EPI == 0) v = fmaxf(v, 0.f);
                C[(size_t)(row0 + r) * N + col] = f2b(v);
            }
        }
    }
}

// ---------------------------------------------------------------------------
// Fused GEMM3 + sigmoid + gate, BK=64 + swizzled LDS.
// out = gi*iQ + gf*ffn (f32). Epilogue reads iQb (bf16) instead of f32 iQ:
// drops a 32 MB stream for the resident 16 MB copy; bf16 rel err <= 2^-9 on
// |iQ|<=5 adds <= ~0.01 abs (threshold 0.0775, measured absmax 0.0156).
// ---------------------------------------------------------------------------
__global__ __launch_bounds__(256, 2)
void gemm_gate_kernel(const u16* __restrict__ iQb, const u16* __restrict__ ffn,
                      const u16* __restrict__ Wgt, const float* __restrict__ bg,
                      float* __restrict__ out, int M, int D2 /*2048*/) {
    __shared__ u16 As [128 * 64];
    __shared__ u16 Bs0[128 * 64];
    __shared__ u16 Bs1[128 * 64];

    const int tid  = threadIdx.x;
    const int m0   = blockIdx.x * 128;
    const int n0   = blockIdx.y * 128;          // out-col tile, n0 < 1024
    const int wave = tid >> 6, lane = tid & 63;
    const int wm   = (wave & 1) << 6;
    const int wn   = (wave >> 1) << 6;
    const int quad = lane >> 4, l16 = lane & 15;
    const int D = D2 >> 1;                      // 1024

    f32x4 acc[2][4][4];
    #pragma unroll
    for (int p = 0; p < 2; ++p)
        #pragma unroll
        for (int i = 0; i < 4; ++i)
            #pragma unroll
            for (int j = 0; j < 4; ++j) acc[p][i][j] = (f32x4){0.f, 0.f, 0.f, 0.f};

    int oo[4], rr[4], qq[4];
    #pragma unroll
    for (int j = 0; j < 4; ++j) {
        oo[j] = tid * 16 + j * 4096;
        rr[j] = oo[j] >> 7;
        qq[j] = ((oo[j] >> 4) & 7) ^ (rr[j] & 7);
    }

    const int ktiles = D2 >> 6;                 // 32
    for (int kt = 0; kt < ktiles; ++kt) {
        const int kb = kt << 6;
        const char* Ab = (const char*)((kb < D) ? (iQb + kb) : (ffn + (kb - D)));
        const char* B0 = (const char*)(Wgt + (size_t)n0 * D2 + kb);
        const char* B1 = (const char*)(Wgt + (size_t)(n0 + D) * D2 + kb);
        #pragma unroll
        for (int j = 0; j < 4; ++j) {
            G2L16(Ab + (size_t)(m0 + rr[j]) * D * 2 + qq[j] * 16, (char*)As  + oo[j]);
            G2L16(B0 + (size_t)rr[j] * D2 * 2 + qq[j] * 16,       (char*)Bs0 + oo[j]);
            G2L16(B1 + (size_t)rr[j] * D2 * 2 + qq[j] * 16,       (char*)Bs1 + oo[j]);
        }
        __syncthreads();

        #pragma unroll
        for (int h = 0; h < 2; ++h) {
            short8 af[4], bf0[4], bf1[4];
            #pragma unroll
            for (int mi = 0; mi < 4; ++mi) {
                const int R = wm + mi * 16 + l16;
                af[mi] = *(const short8*)(As + R * 64 + ((((h << 2) | quad) ^ (R & 7)) << 3));
            }
            #pragma unroll
            for (int ni = 0; ni < 4; ++ni) {
                const int R = wn + ni * 16 + l16;
                const int so = R * 64 + ((((h << 2) | quad) ^ (R & 7)) << 3);
                bf0[ni] = *(const short8*)(Bs0 + so);
                bf1[ni] = *(const short8*)(Bs1 + so);
            }
            #pragma unroll
            for (int mi = 0; mi < 4; ++mi)
                #pragma unroll
                for (int ni = 0; ni < 4; ++ni) {
                    acc[0][mi][ni] = __builtin_amdgcn_mfma_f32_16x16x32_bf16(
                        af[mi], bf0[ni], acc[0][mi][ni], 0, 0, 0);
                    acc[1][mi][ni] = __builtin_amdgcn_mfma_f32_16x16x32_bf16(
                        af[mi], bf1[ni], acc[1][mi][ni], 0, 0, 0);
                }
        }
        __syncthreads();
    }

    #pragma unroll
    for (int ni = 0; ni < 4; ++ni) {
        const int col = n0 + wn + ni * 16 + l16;
        const float bgi = bg[col];
        const float bgf = bg[col + D];
        #pragma unroll
        for (int mi = 0; mi < 4; ++mi) {
            const int row0 = m0 + wm + mi * 16 + quad * 4;
            #pragma unroll
            for (int r = 0; r < 4; ++r) {
                const size_t idx = (size_t)(row0 + r) * D + col;
                const float gi = 1.0f / (1.0f + __expf(-(acc[0][mi][ni][r] + bgi)));
                const float gf = 1.0f / (1.0f + __expf(-(acc[1][mi][ni][r] + bgf)));
                out[idx] = gi * b2f(iQb[idx]) + gf * b2f(ffn[idx]);
            }
        }
    }
}

// ---------------------------------------------------------------------------
extern "C" void kernel_launch(void* const* d_in, const int* in_sizes, int n_in,
                              void* d_out, int out_size, void* d_ws, size_t ws_size,
                              hipStream_t stream) {
    const int B = 4, S = 2048, D = 1024, D2 = 2048;
    const int M = B * S;  // 8192

    const float* iQ = (const float*)d_in[0];
    const float* iV = (const float*)d_in[1];
    const float* W1 = (const float*)d_in[2];
    const float* b1 = (const float*)d_in[3];
    const float* W2 = (const float*)d_in[4];
    const float* b2 = (const float*)d_in[5];
    const float* Wg = (const float*)d_in[6];
    const float* bg = (const float*)d_in[7];
    float* out = (float*)d_out;

    // workspace, no aliasing (62 MB):
    u16*   regA = (u16*)d_ws;                    // avg -> ffn   (16 MB)
    u16*   regB = regA + (size_t)M * D;          // h            (16 MB)
    u16*   iQb  = regB + (size_t)M * D;          // iQ bf16      (16 MB)
    u16*   W1t  = iQb  + (size_t)M * D;          //              ( 2 MB)
    u16*   W2t  = W1t  + (size_t)D * D;          //              ( 2 MB)
    u16*   Wgt  = W2t  + (size_t)D * D;          //              ( 8 MB)
    float* csum = (float*)(Wgt + (size_t)D2 * D2); // B*128*D f32 ( 2 MB)

    u16* avg = regA;
    u16* ffn = regA;
    u16* h   = regB;

    // 1. all independent prologue work in one big dispatch (14848 blocks)
    prologue_kernel<<<14848, 256, 0, stream>>>(W1, W1t, W2, W2t, Wg, Wgt,
                                               iQ, iQb, iV, csum);
    // 2. causal cumulative mean (16-row chunks, 512 blocks)
    scan_kernel<<<B * 128, 256, 0, stream>>>(iV, csum, avg);
    // 3. h = relu(avg @ W1 + b1)   (BK=128 windows)
    gemm_kernel<0><<<dim3(M / 128, D / 128), 256, 0, stream>>>(avg, W1t, b1, h, M, D, D);
    // 4. ffn = h @ W2 + b2   (overlays avg)
    gemm_kernel<1><<<dim3(M / 128, D / 128), 256, 0, stream>>>(h, W2t, b2, ffn, M, D, D);
    // 5. fused gate GEMM + sigmoid-gate epilogue (bf16 iQ in epilogue)
    gemm_gate_kernel<<<dim3(M / 128, D / 128), 256, 0, stream>>>(
        iQb, ffn, Wgt, bg, out, M, D2);
}